// Round 6
// baseline (968.463 us; speedup 1.0000x reference)
//
#include <hip/hip_runtime.h>
#include <math.h>

#define NF 39
#define ND 13
#define NS 26                         // sparse fields
#define KDIM 16
#define FEAT 260013
#define NPAIRS (NF * (NF + 1) / 2)    // 780 unordered pairs (i<=j)
#define PAIR_SLOTS 832                // 13 passes * 64 slots (4 lanes/pair)
#define CPASSES 13
#define SORT_BINS 10000               // features per sparse field

#define CHUNKF4 (NF * 4)              // 156 f4 per (sample, sparse-field) tile row
#define CHUNKF4_PAD 157
#define GR 32                         // ranks per gather block
#define GTH 512

// ---------- K1: per-field counting sort of samples by feature ----------
__global__ __launch_bounds__(256) void ffm_sort(
    const float* __restrict__ x, const int* __restrict__ offsets,
    int* __restrict__ sortF, int* __restrict__ sortB, int B)
{
    __shared__ int hist[SORT_BINS];      // 40,000 B
    __shared__ int stripBase[256];
    const int tid = threadIdx.x;
    const int js  = blockIdx.x;          // 0..25
    const int j   = ND + js;
    const int off = offsets[j];

    for (int i = tid; i < SORT_BINS; i += 256) hist[i] = 0;
    __syncthreads();
    for (int b = tid; b < B; b += 256) {
        int fl = (int)floorf(x[(size_t)b * NF + j]);
        atomicAdd(&hist[fl], 1);
    }
    __syncthreads();

    // exclusive prefix over 10000 bins: per-thread 40-strip, then strip scan
    const int STRIP = (SORT_BINS + 255) / 256;   // 40
    int base = tid * STRIP;
    int sum  = 0;
    for (int k = 0; k < STRIP; ++k) {
        int idx = base + k;
        if (idx < SORT_BINS) { int v = hist[idx]; hist[idx] = sum; sum += v; }
    }
    stripBase[tid] = sum;
    __syncthreads();
    if (tid == 0) {
        int run = 0;
        for (int t = 0; t < 256; ++t) { int v = stripBase[t]; stripBase[t] = run; run += v; }
    }
    __syncthreads();
    int sb = stripBase[tid];
    for (int k = 0; k < STRIP; ++k) {
        int idx = base + k;
        if (idx < SORT_BINS) hist[idx] += sb;
    }
    __syncthreads();

    for (int b = tid; b < B; b += 256) {
        int fl = (int)floorf(x[(size_t)b * NF + j]);
        int r  = atomicAdd(&hist[fl], 1);     // rank (order within bin arbitrary)
        sortF[(size_t)js * B + r] = off + fl;
        sortB[(size_t)js * B + r] = b;
    }
}

// ---------- K2: monotonic gather -> per-sample chunk scatter ----------
// Block = (field js, 32-rank window). Loads W[i][f_sorted] for all 39 rows:
// addresses monotonic within each (row,window) -> DRAM row-buffer friendly;
// duplicate features hit L1. Writes each rank's 2,496B chunk to
// GEb[b][js][i][16] (2.5KB-granular scatter).
__global__ __launch_bounds__(GTH) void ffm_gather(
    const float4* __restrict__ W4,     // [39 * FEAT * 4] f4
    const int*    __restrict__ sortF,  // [NS * B]
    const int*    __restrict__ sortB,  // [NS * B]
    float4*       __restrict__ GEb,    // [B * NS * 156] f4
    int B)
{
    __shared__ float4 sG[GR * CHUNKF4];   // 79,872 B -> 2 blocks/CU
    __shared__ int    sF[GR], sB[GR];
    const int tid   = threadIdx.x;
    const int js    = blockIdx.x % NS;
    const int chunk = blockIdx.x / NS;
    const int rbase = chunk * GR;
    if (rbase >= B) return;
    const int rcnt = (B - rbase < GR) ? (B - rbase) : GR;

    if (tid < rcnt) {
        sF[tid] = sortF[(size_t)js * B + rbase + tid];
        sB[tid] = sortB[(size_t)js * B + rbase + tid];
    }
    __syncthreads();

    // load 39*GR vectors; v = i*GR + r so consecutive vectors = consecutive
    // sorted ranks (adjacent addresses)
    const int q = tid & 3;
    for (int v = tid >> 2; v < NF * GR; v += GTH >> 2) {
        int i = v / GR;
        int r = v - i * GR;
        if (r < rcnt)
            sG[r * CHUNKF4 + (i << 2) + q] =
                W4[((size_t)i * FEAT + sF[r]) * 4 + q];
    }
    __syncthreads();

    for (int o = tid; o < GR * CHUNKF4; o += GTH) {
        int r = o / CHUNKF4;
        int w = o - r * CHUNKF4;
        if (r < rcnt)
            GEb[((size_t)sB[r] * NS + js) * CHUNKF4 + w] = sG[o];
    }
}

// ---------- K3: per-sample compute from contiguous tile ----------
// Stage the sample's contiguous 64,896B GEb tile into LDS; 780 pair-dots
// (4 lanes/pair); dense-side vectors come from the sample-invariant 32KB
// W[r][offsets[d]] set (L2-hot). Linear term + sigmoid fused. No atomics.
__global__ __launch_bounds__(256) void ffm_compute(
    const float*  __restrict__ x,       // [B, 39]
    const float4* __restrict__ W4,      // [39 * FEAT * 4] f4
    const float4* __restrict__ GEb,     // [B * NS * 156] f4
    const float*  __restrict__ fc_w,    // [FEAT]
    const float*  __restrict__ bias,    // [1]
    const int*    __restrict__ offsets, // [39]
    float*        __restrict__ out,     // [B]
    int B)
{
    __shared__ float4         sT[NS * CHUNKF4_PAD];  // 65,312 B
    __shared__ float          sxm[NF];
    __shared__ int            soff[NF];
    __shared__ unsigned short spij[PAIR_SLOTS];
    __shared__ float          swst[PAIR_SLOTS];
    __shared__ float          sred[4];

    const int b   = blockIdx.x;
    const int tid = threadIdx.x;

    if (tid < NF) {
        float xv  = x[(size_t)b * NF + tid];
        sxm[tid]  = (tid < ND) ? xv : 1.0f;
        soff[tid] = offsets[tid];
    }
    // static pair table + structural weight:
    //   i==j<38: 1 ; i<j<38: 2 ; i<j==38: 1 ; (38,38): 0 ; padding: 0
    for (int p = tid; p < PAIR_SLOTS; p += 256) {
        int i = 0, jj = 0; float w = 0.0f;
        if (p < NPAIRS) {
            int base = 0, ii = 0;
            while (p >= base + (NF - ii)) { base += NF - ii; ++ii; }
            i = ii; jj = ii + (p - base);
            if (i == jj)          w = (i < NF - 1) ? 1.0f : 0.0f;
            else if (jj < NF - 1) w = 2.0f;
            else                  w = 1.0f;
        }
        spij[p] = (unsigned short)(i | (jj << 8));
        swst[p] = w;
    }

    // stage tile: contiguous 4056-f4 stream -> padded LDS
    for (int o = tid; o < NS * CHUNKF4; o += 256) {
        int c = o / CHUNKF4;
        int w = o - c * CHUNKF4;
        sT[c * CHUNKF4_PAD + w] = GEb[(size_t)b * (NS * CHUNKF4) + o];
    }
    __syncthreads();

    float acc = 0.0f;
    if (tid < NF) {    // linear term
        float xv = x[(size_t)b * NF + tid];
        int f    = ((tid < ND) ? 0 : (int)floorf(xv)) + soff[tid];
        acc = fc_w[f];
    }

    const int slot = tid >> 2;
    const int q    = tid & 3;

    #pragma unroll 4
    for (int pass = 0; pass < CPASSES; ++pass) {
        int   p   = pass * 64 + slot;
        int   ij  = spij[p];
        int   i   = ij & 0xff;
        int   j   = ij >> 8;
        float wgt = swst[p] * sxm[i] * sxm[j];

        // a = W[i][f_j] ; v = W[j][f_i]
        float4 a = (j >= ND) ? sT[(j - ND) * CHUNKF4_PAD + (i << 2) + q]
                             : W4[((size_t)i * FEAT + soff[j]) * 4 + q];
        float4 v = (i >= ND) ? sT[(i - ND) * CHUNKF4_PAD + (j << 2) + q]
                             : W4[((size_t)j * FEAT + soff[i]) * 4 + q];

        acc += wgt * (a.x * v.x + a.y * v.y + a.z * v.z + a.w * v.w);
    }

    #pragma unroll
    for (int off = 32; off > 0; off >>= 1)
        acc += __shfl_down(acc, off, 64);
    if ((tid & 63) == 0) sred[tid >> 6] = acc;
    __syncthreads();

    if (tid == 0) {
        float z = sred[0] + sred[1] + sred[2] + sred[3] + bias[0];
        out[b] = 1.0f / (1.0f + expf(-z));
    }
}

// ---- fallback: verified round-0 kernel (native W layout, 8 lanes/pair) ----
#define PASSES ((NPAIRS + 31) / 32)
__global__ __launch_bounds__(256) void ffm_kernel(
    const float* __restrict__ x, const float* __restrict__ W,
    const float* __restrict__ fc_w, const float* __restrict__ bias,
    const int* __restrict__ offsets, float* __restrict__ out, int B)
{
    __shared__ int            sf[NF];
    __shared__ float          sxm[NF];
    __shared__ unsigned short spij[NPAIRS];
    __shared__ float          sred[4];

    const int b   = blockIdx.x;
    const int tid = threadIdx.x;

    if (tid < NF) {
        float xv = x[(size_t)b * NF + tid];
        int idx  = (tid < ND) ? 0 : (int)floorf(xv);
        sf[tid]  = idx + offsets[tid];
        sxm[tid] = (tid < ND) ? xv : 1.0f;
    }
    for (int p = tid; p < NPAIRS; p += 256) {
        int i = 0, base = 0;
        while (p >= base + (NF - i)) { base += NF - i; ++i; }
        int j = i + (p - base);
        spij[p] = (unsigned short)(i | (j << 8));
    }
    __syncthreads();

    const int slot = tid >> 3;
    const int quad = (tid >> 2) & 1;
    const int qi   = tid & 3;

    float acc = 0.0f;
    if (tid < NF) acc += fc_w[sf[tid]];

    #pragma unroll 5
    for (int pass = 0; pass < PASSES; ++pass) {
        int p  = pass * 32 + slot;
        int pc = (p < NPAIRS) ? p : (NPAIRS - 1);
        int ij = spij[pc];
        int i  = ij & 0xff;
        int j  = ij >> 8;

        float w;
        if (i == j)          w = (i < NF - 1) ? sxm[i] * sxm[i] : 0.0f;
        else if (j < NF - 1) w = 2.0f * sxm[i] * sxm[j];
        else                 w = sxm[i] * sxm[j];
        if (p >= NPAIRS) w = 0.0f;

        int row  = quad ? j : i;
        int feat = quad ? sf[i] : sf[j];
        const float4* vp = (const float4*)(W + ((size_t)row * FEAT + feat) * KDIM);
        float4 v = vp[qi];

        float4 u;
        u.x = __shfl_xor(v.x, 4, 64);
        u.y = __shfl_xor(v.y, 4, 64);
        u.z = __shfl_xor(v.z, 4, 64);
        u.w = __shfl_xor(v.w, 4, 64);

        float d = v.x * u.x + v.y * u.y + v.z * u.z + v.w * u.w;
        acc += 0.5f * w * d;
    }

    #pragma unroll
    for (int off = 32; off > 0; off >>= 1)
        acc += __shfl_down(acc, off, 64);
    if ((tid & 63) == 0) sred[tid >> 6] = acc;
    __syncthreads();

    if (tid == 0) {
        float z = sred[0] + sred[1] + sred[2] + sred[3] + bias[0];
        out[b] = 1.0f / (1.0f + expf(-z));
    }
}

extern "C" void kernel_launch(void* const* d_in, const int* in_sizes, int n_in,
                              void* d_out, int out_size, void* d_ws, size_t ws_size,
                              hipStream_t stream) {
    const float* x       = (const float*)d_in[0];
    const float* W       = (const float*)d_in[1];
    const float* fc_w    = (const float*)d_in[2];
    const float* bias    = (const float*)d_in[3];
    const int*   offsets = (const int*)d_in[4];

    float* out = (float*)d_out;
    const int B = in_sizes[0] / NF;

    // workspace: GEb [B*NS*156] f4 | sortF [NS*B] int | sortB [NS*B] int
    const size_t GE_BYTES = (size_t)B * NS * CHUNKF4 * sizeof(float4); // ~266 MB
    const size_t SF_BYTES = (size_t)NS * B * sizeof(int);
    const size_t NEED     = GE_BYTES + 2 * SF_BYTES + 256;

    if (d_ws != nullptr && ws_size >= NEED) {
        float4* GEb   = (float4*)d_ws;
        int*    sortF = (int*)((char*)d_ws + GE_BYTES);
        int*    sortB = (int*)((char*)d_ws + GE_BYTES + SF_BYTES);

        ffm_sort<<<NS, 256, 0, stream>>>(x, offsets, sortF, sortB, B);

        const int nchunks = (B + GR - 1) / GR;
        ffm_gather<<<NS * nchunks, GTH, 0, stream>>>(
            (const float4*)W, sortF, sortB, GEb, B);

        ffm_compute<<<B, 256, 0, stream>>>(x, (const float4*)W, GEb, fc_w,
                                           bias, offsets, out, B);
    } else {
        ffm_kernel<<<B, 256, 0, stream>>>(x, W, fc_w, bias, offsets, out, B);
    }
}